// Round 7
// baseline (335.072 us; speedup 1.0000x reference)
//
#include <hip/hip_runtime.h>
#include <math.h>

#define Nn 6144
#define Cc 128
#define NHD 2
#define MAXDEG 1024

// ---------------- warp/block reduction helpers ----------------
__device__ __forceinline__ float wave_red_sum(float v) {
#pragma unroll
  for (int o = 32; o; o >>= 1) v += __shfl_xor(v, o);
  return v;
}

template <bool IS_MAX>
__device__ __forceinline__ void block_red2(float& a, float& b, float* red) {
#pragma unroll
  for (int o = 32; o; o >>= 1) {
    float ta = __shfl_xor(a, o), tb = __shfl_xor(b, o);
    if (IS_MAX) { a = fmaxf(a, ta); b = fmaxf(b, tb); }
    else        { a += ta;          b += tb;          }
  }
  int wid = threadIdx.x >> 6;
  __syncthreads();
  if ((threadIdx.x & 63) == 0) { red[wid] = a; red[4 + wid] = b; }
  __syncthreads();
  if (IS_MAX) {
    a = fmaxf(fmaxf(red[0], red[1]), fmaxf(red[2], red[3]));
    b = fmaxf(fmaxf(red[4], red[5]), fmaxf(red[6], red[7]));
  } else {
    a = red[0] + red[1] + red[2] + red[3];
    b = red[4] + red[5] + red[6] + red[7];
  }
}

// ---------------- fused LN + FF0 GEMM + attn_s ------------------------------
// UNCHANGED from round-6 verified version (control for this round's delta).
__global__ __launch_bounds__(256) void k_ff0_fused(
    const float* __restrict__ x, const float* __restrict__ g1,
    const float* __restrict__ b1, const float* __restrict__ Bw,
    const float* __restrict__ aw, float* __restrict__ h,
    float* __restrict__ ssrc, float* __restrict__ sdst) {
  __shared__ float Axn[128][36];
  __shared__ float Bs[64][132];
  const int t = threadIdx.x;
  const int head = blockIdx.y;
  const int row0 = blockIdx.x * 32;
  const float* Bh = Bw + (size_t)head * Cc * Cc;

  {
    const int row = t >> 3, seg = t & 7;
    const int cb = seg * 16;
    const float* xr = x + (size_t)(row0 + row) * Cc + cb;
    float v[16], gg[16], bb[16];
#pragma unroll
    for (int i = 0; i < 16; i += 4) {
      float4 t4 = *(const float4*)(xr + i);
      v[i] = t4.x; v[i + 1] = t4.y; v[i + 2] = t4.z; v[i + 3] = t4.w;
      float4 g4 = *(const float4*)(g1 + cb + i);
      gg[i] = g4.x; gg[i + 1] = g4.y; gg[i + 2] = g4.z; gg[i + 3] = g4.w;
      float4 b4 = *(const float4*)(b1 + cb + i);
      bb[i] = b4.x; bb[i + 1] = b4.y; bb[i + 2] = b4.z; bb[i + 3] = b4.w;
    }
    float s = 0.f;
#pragma unroll
    for (int i = 0; i < 16; i++) s += v[i];
    s += __shfl_xor(s, 1); s += __shfl_xor(s, 2); s += __shfl_xor(s, 4);
    float mean = s * (1.0f / 128.0f);
    float q = 0.f;
#pragma unroll
    for (int i = 0; i < 16; i++) { float d_ = v[i] - mean; q += d_ * d_; }
    q += __shfl_xor(q, 1); q += __shfl_xor(q, 2); q += __shfl_xor(q, 4);
    float rstd = rsqrtf(q * (1.0f / 128.0f) + 1e-5f);
#pragma unroll
    for (int i = 0; i < 16; i++)
      Axn[cb + i][row] = (v[i] - mean) * rstd * gg[i] + bb[i];
  }
  __syncthreads();

  const int tr = t & 7, tc = t >> 3;
  float acc[4][4];
#pragma unroll
  for (int i = 0; i < 4; i++)
#pragma unroll
    for (int j = 0; j < 4; j++) acc[i][j] = 0.f;

  for (int kt = 0; kt < Cc; kt += 64) {
    for (int i = t; i < 2048; i += 256) {
      int cc2 = i >> 4, k4 = i & 15;
      float4 v = *(const float4*)(Bh + (size_t)cc2 * Cc + kt + k4 * 4);
      Bs[k4 * 4 + 0][cc2] = v.x; Bs[k4 * 4 + 1][cc2] = v.y;
      Bs[k4 * 4 + 2][cc2] = v.z; Bs[k4 * 4 + 3][cc2] = v.w;
    }
    __syncthreads();
#pragma unroll
    for (int k = 0; k < 64; k++) {
      float4 a4 = *(const float4*)&Axn[kt + k][tr * 4];
      float4 b4 = *(const float4*)&Bs[k][tc * 4];
      float av[4] = {a4.x, a4.y, a4.z, a4.w};
      float bv[4] = {b4.x, b4.y, b4.z, b4.w};
#pragma unroll
      for (int i = 0; i < 4; i++)
#pragma unroll
        for (int j = 0; j < 4; j++) acc[i][j] = fmaf(av[i], bv[j], acc[i][j]);
    }
    __syncthreads();
  }

  float psrc[4], pdst[4];
  {
    float4 w1 = *(const float4*)(aw + head * 2 * Cc + tc * 4);
    float4 w2 = *(const float4*)(aw + head * 2 * Cc + Cc + tc * 4);
#pragma unroll
    for (int i = 0; i < 4; i++) {
      float* op = h + ((size_t)head * Nn + row0 + tr * 4 + i) * Cc + tc * 4;
      *(float4*)op = make_float4(acc[i][0], acc[i][1], acc[i][2], acc[i][3]);
      psrc[i] = acc[i][0] * w1.x + acc[i][1] * w1.y + acc[i][2] * w1.z + acc[i][3] * w1.w;
      pdst[i] = acc[i][0] * w2.x + acc[i][1] * w2.y + acc[i][2] * w2.z + acc[i][3] * w2.w;
    }
  }
  float* epart = &Bs[0][0];  // [32 tc][32 row][2]
#pragma unroll
  for (int i = 0; i < 4; i++) {
    epart[((tc * 32) + (tr * 4 + i)) * 2 + 0] = psrc[i];
    epart[((tc * 32) + (tr * 4 + i)) * 2 + 1] = pdst[i];
  }
  __syncthreads();
  if (t < 64) {
    int row = t >> 1, s = t & 1;
    float v = 0.f;
#pragma unroll
    for (int g = 0; g < 32; g++) v += epart[(g * 32 + row) * 2 + s];
    (s ? sdst : ssrc)[head * Nn + row0 + row] = v;
  }
}

// ---------------- fused attention + residual + LN2 + FF1 + head-combine ----
// One block per row. Phases A-D as in the round-6 verified k_attn, then an
// FF1 epilogue: each thread computes one (head, c_out) dot over k=128 from
// the LN'd att row held in LDS, ff1 weights streamed from L2 (128KB,
// fully L2-resident). Eliminates k_ff1_comb + the 12.6MB attn round-trip.
__global__ __launch_bounds__(256) void k_attn_ff1(
    const float* __restrict__ adj, const float* __restrict__ x,
    const float* __restrict__ h, const float* __restrict__ ssrc,
    const float* __restrict__ sdst, const float* __restrict__ g2,
    const float* __restrict__ b2, const float* __restrict__ ff1,
    float* __restrict__ out) {
  __shared__ __align__(16) int nbr[MAXDEG];          // aliased: attbuf, combuf
  __shared__ __align__(16) float wts[NHD][MAXDEG];   // aliased: part, lnbuf
  __shared__ float red[8];
  __shared__ int cnt;
  const int t = threadIdx.x;
  const int r = blockIdx.x;
  if (t == 0) cnt = 0;
  __syncthreads();
  // phase A: adjacency scan -> compact neighbor list (plus self-loop)
  const float4* arow = (const float4*)(adj + (size_t)r * Nn);
  for (int i = t; i < Nn / 4; i += 256) {
    float4 v = arow[i];
    int j = i * 4;
    if (v.x > 0.f || j + 0 == r) { int p = atomicAdd(&cnt, 1); if (p < MAXDEG) nbr[p] = j + 0; }
    if (v.y > 0.f || j + 1 == r) { int p = atomicAdd(&cnt, 1); if (p < MAXDEG) nbr[p] = j + 1; }
    if (v.z > 0.f || j + 2 == r) { int p = atomicAdd(&cnt, 1); if (p < MAXDEG) nbr[p] = j + 2; }
    if (v.w > 0.f || j + 3 == r) { int p = atomicAdd(&cnt, 1); if (p < MAXDEG) nbr[p] = j + 3; }
  }
  __syncthreads();
  const int deg = min(cnt, MAXDEG);
  const float s0 = ssrc[r], s1 = ssrc[Nn + r];
  // phase B1: logits + max
  float m0 = -3.0e38f, m1 = -3.0e38f;
  for (int k = t; k < deg; k += 256) {
    int j = nbr[k];
    float e0 = s0 + sdst[j];
    float e1 = s1 + sdst[Nn + j];
    e0 = (e0 > 0.f) ? e0 : 0.01f * e0;
    e1 = (e1 > 0.f) ? e1 : 0.01f * e1;
    wts[0][k] = e0; wts[1][k] = e1;
    m0 = fmaxf(m0, e0); m1 = fmaxf(m1, e1);
  }
  block_red2<true>(m0, m1, red);
  // phase B2: exp + sum
  float l0 = 0.f, l1 = 0.f;
  for (int k = t; k < deg; k += 256) {
    float w0 = __expf(wts[0][k] - m0); wts[0][k] = w0; l0 += w0;
    float w1 = __expf(wts[1][k] - m1); wts[1][k] = w1; l1 += w1;
  }
  block_red2<false>(l0, l1, red);
  // phase C: weighted gather of h rows (2 heads x 4 groups x 32 chan-quads)
  float att;  // per-thread pre-LN att value for (hd = t>>7, c = t&127)
  {
    const int hd = t >> 7, g = (t >> 5) & 3, c4 = t & 31;
    const float* hp = h + (size_t)hd * Nn * Cc + c4 * 4;
    float4 a4 = make_float4(0.f, 0.f, 0.f, 0.f);
#pragma unroll 2
    for (int k = g; k < deg; k += 4) {
      float w = wts[hd][k];
      const float4 hv = *(const float4*)(hp + (size_t)nbr[k] * Cc);
      a4.x = fmaf(w, hv.x, a4.x);
      a4.y = fmaf(w, hv.y, a4.y);
      a4.z = fmaf(w, hv.z, a4.z);
      a4.w = fmaf(w, hv.w, a4.w);
    }
    __syncthreads();                       // wts/nbr raw contents dead after this
    float4* part = (float4*)&wts[0][0];    // 256 x float4 scratch
    part[t] = a4;
    __syncthreads();
    float* attbuf = (float*)nbr;           // [2][128] floats
    if (t < 64) {
      const int hd2 = t >> 5, cb = t & 31;
      float4 p0 = part[hd2 * 128 + 0  + cb];
      float4 p1 = part[hd2 * 128 + 32 + cb];
      float4 p2 = part[hd2 * 128 + 64 + cb];
      float4 p3 = part[hd2 * 128 + 96 + cb];
      float sx_ = p0.x + p1.x + p2.x + p3.x;
      float sy_ = p0.y + p1.y + p2.y + p3.y;
      float sz_ = p0.z + p1.z + p2.z + p3.z;
      float sw_ = p0.w + p1.w + p2.w + p3.w;
      const float inv2 = 1.0f / (hd2 ? l1 : l0);
      const float4 xv = *(const float4*)(x + (size_t)r * Cc + cb * 4);
      float4 att4;
      att4.x = fmaf(sx_, inv2, xv.x);
      att4.y = fmaf(sy_, inv2, xv.y);
      att4.z = fmaf(sz_, inv2, xv.z);
      att4.w = fmaf(sw_, inv2, xv.w);
      ((float4*)attbuf)[hd2 * 32 + cb] = att4;
    }
    __syncthreads();
    att = ((float*)nbr)[(t >> 7) * 128 + (t & 127)];
  }
  // phase D: LN over 128 channels per head (2 waves per head)
  const int hd = t >> 7, c = t & 127;
  float* lnbuf = (float*)&wts[0][0];  // 256 floats; wts region dead
  {
    float s = wave_red_sum(att);
    int wid = t >> 6;
    __syncthreads();
    if ((t & 63) == 0) red[wid] = s;
    __syncthreads();
    float mean = (red[hd * 2] + red[hd * 2 + 1]) * (1.0f / Cc);
    float d = att - mean;
    float q = wave_red_sum(d * d);
    __syncthreads();
    if ((t & 63) == 0) red[wid] = q;
    __syncthreads();
    float var = (red[hd * 2] + red[hd * 2 + 1]) * (1.0f / Cc);
    float rstd = rsqrtf(var + 1e-5f);
    lnbuf[t] = d * rstd * g2[c] + b2[c];  // t == hd*128 + c
  }
  __syncthreads();
  // phase E: FF1 + elu*0.5 per (head, c_out); weights L2-resident
  {
    const float* wrow = ff1 + ((size_t)hd * Cc + c) * Cc;  // ff1[hd][c][*]
    const float4* ln4 = (const float4*)(lnbuf + hd * 128); // broadcast reads
    float acc = 0.f;
#pragma unroll 8
    for (int k4 = 0; k4 < 32; k4++) {
      float4 w4 = *(const float4*)(wrow + k4 * 4);
      float4 a4 = ln4[k4];
      acc += a4.x * w4.x + a4.y * w4.y + a4.z * w4.z + a4.w * w4.w;
    }
    acc = (acc > 0.f) ? acc : (expf(acc) - 1.f);
    acc *= 0.5f;
    // head-combine via LDS (nbr region; attbuf reads all done pre-phase-D sync)
    float* combuf = (float*)nbr;
    combuf[t] = acc;
    __syncthreads();
    if (t < 128) out[(size_t)r * Cc + t] = combuf[t] + combuf[128 + t];
  }
}

extern "C" void kernel_launch(void* const* d_in, const int* in_sizes, int n_in,
                              void* d_out, int out_size, void* d_ws, size_t ws_size,
                              hipStream_t stream) {
  const float* x   = (const float*)d_in[0];
  const float* adj = (const float*)d_in[1];
  const float* ff0 = (const float*)d_in[2];
  const float* ff1 = (const float*)d_in[3];
  const float* aw  = (const float*)d_in[4];
  const float* g1  = (const float*)d_in[5];
  const float* b1  = (const float*)d_in[6];
  const float* g2  = (const float*)d_in[7];
  const float* b2  = (const float*)d_in[8];
  float* out = (float*)d_out;

  float* ws   = (float*)d_ws;
  float* h    = ws;                                  // 2*Nn*Cc
  float* ssrc = h + (size_t)2 * Nn * Cc;             // 2*Nn
  float* sdst = ssrc + 2 * Nn;                       // 2*Nn
  // total ws use: ~6.4 MB (fp32)

  hipLaunchKernelGGL(k_ff0_fused, dim3(Nn / 32, NHD), dim3(256), 0, stream,
                     x, g1, b1, ff0, aw, h, ssrc, sdst);
  hipLaunchKernelGGL(k_attn_ff1, dim3(Nn), dim3(256), 0, stream,
                     adj, x, h, ssrc, sdst, g2, b2, ff1, out);
}

// Round 8
// 304.178 us; speedup vs baseline: 1.1016x; 1.1016x over previous
//
#include <hip/hip_runtime.h>
#include <math.h>

#define Nn 6144
#define Cc 128
#define NHD 2
#define GMAXDEG 256  // deg ~ Binomial(6144,0.01): mean 61, sd 7.8; 256 = +25 sigma

// ---------------- warp/block reduction helpers ----------------
__device__ __forceinline__ float wave_red_sum(float v) {
#pragma unroll
  for (int o = 32; o; o >>= 1) v += __shfl_xor(v, o);
  return v;
}

template <bool IS_MAX>
__device__ __forceinline__ void block_red2(float& a, float& b, float* red) {
#pragma unroll
  for (int o = 32; o; o >>= 1) {
    float ta = __shfl_xor(a, o), tb = __shfl_xor(b, o);
    if (IS_MAX) { a = fmaxf(a, ta); b = fmaxf(b, tb); }
    else        { a += ta;          b += tb;          }
  }
  int wid = threadIdx.x >> 6;
  __syncthreads();
  if ((threadIdx.x & 63) == 0) { red[wid] = a; red[4 + wid] = b; }
  __syncthreads();
  if (IS_MAX) {
    a = fmaxf(fmaxf(red[0], red[1]), fmaxf(red[2], red[3]));
    b = fmaxf(fmaxf(red[4], red[5]), fmaxf(red[6], red[7]));
  } else {
    a = red[0] + red[1] + red[2] + red[3];
    b = red[4] + red[5] + red[6] + red[7];
  }
}

// ---------------- kernel 0: adjacency scan -> CSR (pure streaming) ----------
// One lean block per row: read 24.6KB, compact matches in LDS, dump list.
// 151MB total read -> 24us floor at 6.3TB/s; nothing else to serialize.
__global__ __launch_bounds__(256) void k_scan(const float* __restrict__ adj,
                                              int* __restrict__ degp,
                                              int* __restrict__ nbrg) {
  __shared__ int nbr[GMAXDEG];
  __shared__ int cnt;
  const int t = threadIdx.x;
  const int r = blockIdx.x;
  if (t == 0) cnt = 0;
  __syncthreads();
  const float4* arow = (const float4*)(adj + (size_t)r * Nn);
  for (int i = t; i < Nn / 4; i += 256) {
    float4 v = arow[i];
    int j = i * 4;
    if (v.x > 0.f || j + 0 == r) { int p = atomicAdd(&cnt, 1); if (p < GMAXDEG) nbr[p] = j + 0; }
    if (v.y > 0.f || j + 1 == r) { int p = atomicAdd(&cnt, 1); if (p < GMAXDEG) nbr[p] = j + 1; }
    if (v.z > 0.f || j + 2 == r) { int p = atomicAdd(&cnt, 1); if (p < GMAXDEG) nbr[p] = j + 2; }
    if (v.w > 0.f || j + 3 == r) { int p = atomicAdd(&cnt, 1); if (p < GMAXDEG) nbr[p] = j + 3; }
  }
  __syncthreads();
  const int d = min(cnt, GMAXDEG);
  if (t == 0) degp[r] = d;
  for (int k = t; k < d; k += 256) nbrg[(size_t)r * GMAXDEG + k] = nbr[k];
}

// ---------------- fused LN + FF0 GEMM + attn_s ------------------------------
// UNCHANGED from round-6 verified version (control).
__global__ __launch_bounds__(256) void k_ff0_fused(
    const float* __restrict__ x, const float* __restrict__ g1,
    const float* __restrict__ b1, const float* __restrict__ Bw,
    const float* __restrict__ aw, float* __restrict__ h,
    float* __restrict__ ssrc, float* __restrict__ sdst) {
  __shared__ float Axn[128][36];
  __shared__ float Bs[64][132];
  const int t = threadIdx.x;
  const int head = blockIdx.y;
  const int row0 = blockIdx.x * 32;
  const float* Bh = Bw + (size_t)head * Cc * Cc;

  {
    const int row = t >> 3, seg = t & 7;
    const int cb = seg * 16;
    const float* xr = x + (size_t)(row0 + row) * Cc + cb;
    float v[16], gg[16], bb[16];
#pragma unroll
    for (int i = 0; i < 16; i += 4) {
      float4 t4 = *(const float4*)(xr + i);
      v[i] = t4.x; v[i + 1] = t4.y; v[i + 2] = t4.z; v[i + 3] = t4.w;
      float4 g4 = *(const float4*)(g1 + cb + i);
      gg[i] = g4.x; gg[i + 1] = g4.y; gg[i + 2] = g4.z; gg[i + 3] = g4.w;
      float4 b4 = *(const float4*)(b1 + cb + i);
      bb[i] = b4.x; bb[i + 1] = b4.y; bb[i + 2] = b4.z; bb[i + 3] = b4.w;
    }
    float s = 0.f;
#pragma unroll
    for (int i = 0; i < 16; i++) s += v[i];
    s += __shfl_xor(s, 1); s += __shfl_xor(s, 2); s += __shfl_xor(s, 4);
    float mean = s * (1.0f / 128.0f);
    float q = 0.f;
#pragma unroll
    for (int i = 0; i < 16; i++) { float d_ = v[i] - mean; q += d_ * d_; }
    q += __shfl_xor(q, 1); q += __shfl_xor(q, 2); q += __shfl_xor(q, 4);
    float rstd = rsqrtf(q * (1.0f / 128.0f) + 1e-5f);
#pragma unroll
    for (int i = 0; i < 16; i++)
      Axn[cb + i][row] = (v[i] - mean) * rstd * gg[i] + bb[i];
  }
  __syncthreads();

  const int tr = t & 7, tc = t >> 3;
  float acc[4][4];
#pragma unroll
  for (int i = 0; i < 4; i++)
#pragma unroll
    for (int j = 0; j < 4; j++) acc[i][j] = 0.f;

  for (int kt = 0; kt < Cc; kt += 64) {
    for (int i = t; i < 2048; i += 256) {
      int cc2 = i >> 4, k4 = i & 15;
      float4 v = *(const float4*)(Bh + (size_t)cc2 * Cc + kt + k4 * 4);
      Bs[k4 * 4 + 0][cc2] = v.x; Bs[k4 * 4 + 1][cc2] = v.y;
      Bs[k4 * 4 + 2][cc2] = v.z; Bs[k4 * 4 + 3][cc2] = v.w;
    }
    __syncthreads();
#pragma unroll
    for (int k = 0; k < 64; k++) {
      float4 a4 = *(const float4*)&Axn[kt + k][tr * 4];
      float4 b4 = *(const float4*)&Bs[k][tc * 4];
      float av[4] = {a4.x, a4.y, a4.z, a4.w};
      float bv[4] = {b4.x, b4.y, b4.z, b4.w};
#pragma unroll
      for (int i = 0; i < 4; i++)
#pragma unroll
        for (int j = 0; j < 4; j++) acc[i][j] = fmaf(av[i], bv[j], acc[i][j]);
    }
    __syncthreads();
  }

  float psrc[4], pdst[4];
  {
    float4 w1 = *(const float4*)(aw + head * 2 * Cc + tc * 4);
    float4 w2 = *(const float4*)(aw + head * 2 * Cc + Cc + tc * 4);
#pragma unroll
    for (int i = 0; i < 4; i++) {
      float* op = h + ((size_t)head * Nn + row0 + tr * 4 + i) * Cc + tc * 4;
      *(float4*)op = make_float4(acc[i][0], acc[i][1], acc[i][2], acc[i][3]);
      psrc[i] = acc[i][0] * w1.x + acc[i][1] * w1.y + acc[i][2] * w1.z + acc[i][3] * w1.w;
      pdst[i] = acc[i][0] * w2.x + acc[i][1] * w2.y + acc[i][2] * w2.z + acc[i][3] * w2.w;
    }
  }
  float* epart = &Bs[0][0];  // [32 tc][32 row][2]
#pragma unroll
  for (int i = 0; i < 4; i++) {
    epart[((tc * 32) + (tr * 4 + i)) * 2 + 0] = psrc[i];
    epart[((tc * 32) + (tr * 4 + i)) * 2 + 1] = pdst[i];
  }
  __syncthreads();
  if (t < 64) {
    int row = t >> 1, s = t & 1;
    float v = 0.f;
#pragma unroll
    for (int g = 0; g < 32; g++) v += epart[(g * 32 + row) * 2 + s];
    (s ? sdst : ssrc)[head * Nn + row0 + row] = v;
  }
}

// ---------------- kernel 3: CSR attention + residual + LN2 ------------------
// Phase A replaced by a tiny CSR load; phases B-D identical to round-6 k_attn.
__global__ __launch_bounds__(256) void k_attn(
    const int* __restrict__ degp, const int* __restrict__ nbrg,
    const float* __restrict__ x, const float* __restrict__ h,
    const float* __restrict__ ssrc, const float* __restrict__ sdst,
    const float* __restrict__ g2, const float* __restrict__ b2,
    float* __restrict__ att_out) {
  __shared__ __align__(16) int nbr[GMAXDEG];        // aliased: attbuf (1KB)
  __shared__ __align__(16) float wts[NHD][GMAXDEG]; // aliased: lnbuf (2KB)
  __shared__ __align__(16) float4 part[256];        // 4KB
  __shared__ float red[8];
  const int t = threadIdx.x;
  const int r = blockIdx.x;
  const int deg = degp[r];
  for (int k = t; k < deg; k += 256) nbr[k] = nbrg[(size_t)r * GMAXDEG + k];
  __syncthreads();
  const float s0 = ssrc[r], s1 = ssrc[Nn + r];
  // phase B1: logits + max
  float m0 = -3.0e38f, m1 = -3.0e38f;
  for (int k = t; k < deg; k += 256) {
    int j = nbr[k];
    float e0 = s0 + sdst[j];
    float e1 = s1 + sdst[Nn + j];
    e0 = (e0 > 0.f) ? e0 : 0.01f * e0;
    e1 = (e1 > 0.f) ? e1 : 0.01f * e1;
    wts[0][k] = e0; wts[1][k] = e1;
    m0 = fmaxf(m0, e0); m1 = fmaxf(m1, e1);
  }
  block_red2<true>(m0, m1, red);
  // phase B2: exp + sum
  float l0 = 0.f, l1 = 0.f;
  for (int k = t; k < deg; k += 256) {
    float w0 = __expf(wts[0][k] - m0); wts[0][k] = w0; l0 += w0;
    float w1 = __expf(wts[1][k] - m1); wts[1][k] = w1; l1 += w1;
  }
  block_red2<false>(l0, l1, red);
  // phase C: weighted gather (2 heads x 4 groups x 32 chan-quads)
  {
    const int hd = t >> 7, g = (t >> 5) & 3, c4 = t & 31;
    const float* hp = h + (size_t)hd * Nn * Cc + c4 * 4;
    float4 a4 = make_float4(0.f, 0.f, 0.f, 0.f);
#pragma unroll 2
    for (int k = g; k < deg; k += 4) {
      float w = wts[hd][k];
      const float4 hv = *(const float4*)(hp + (size_t)nbr[k] * Cc);
      a4.x = fmaf(w, hv.x, a4.x);
      a4.y = fmaf(w, hv.y, a4.y);
      a4.z = fmaf(w, hv.z, a4.z);
      a4.w = fmaf(w, hv.w, a4.w);
    }
    __syncthreads();
    part[t] = a4;
    __syncthreads();
    float* attbuf = (float*)nbr;  // 256 floats over nbr (reads all done)
    if (t < 64) {
      const int hd2 = t >> 5, cb = t & 31;
      float4 p0 = part[hd2 * 128 + 0  + cb];
      float4 p1 = part[hd2 * 128 + 32 + cb];
      float4 p2 = part[hd2 * 128 + 64 + cb];
      float4 p3 = part[hd2 * 128 + 96 + cb];
      float sx_ = p0.x + p1.x + p2.x + p3.x;
      float sy_ = p0.y + p1.y + p2.y + p3.y;
      float sz_ = p0.z + p1.z + p2.z + p3.z;
      float sw_ = p0.w + p1.w + p2.w + p3.w;
      const float inv2 = 1.0f / (hd2 ? l1 : l0);
      const float4 xv = *(const float4*)(x + (size_t)r * Cc + cb * 4);
      float4 att4;
      att4.x = fmaf(sx_, inv2, xv.x);
      att4.y = fmaf(sy_, inv2, xv.y);
      att4.z = fmaf(sz_, inv2, xv.z);
      att4.w = fmaf(sw_, inv2, xv.w);
      ((float4*)attbuf)[hd2 * 32 + cb] = att4;
    }
    __syncthreads();
  }
  // phase D: LN over 128 channels per head (2 waves per head)
  {
    const int hd = t >> 7, c = t & 127;
    float att = ((float*)nbr)[hd * 128 + c];
    float s = wave_red_sum(att);
    int wid = t >> 6;
    __syncthreads();
    if ((t & 63) == 0) red[wid] = s;
    __syncthreads();
    float mean = (red[hd * 2] + red[hd * 2 + 1]) * (1.0f / Cc);
    float d = att - mean;
    float q = wave_red_sum(d * d);
    __syncthreads();
    if ((t & 63) == 0) red[wid] = q;
    __syncthreads();
    float var = (red[hd * 2] + red[hd * 2 + 1]) * (1.0f / Cc);
    float rstd = rsqrtf(var + 1e-5f);
    att_out[((size_t)hd * Nn + r) * Cc + c] = d * rstd * g2[c] + b2[c];
  }
}

// ---------------- fused FF1 GEMM + head-combine, 32-row tiles ---------------
// REVERTED to round-6 verified version (round-7 epilogue fusion regressed).
__global__ __launch_bounds__(256) void k_ff1_comb(const float* __restrict__ A,
                                                  const float* __restrict__ Bw,
                                                  float* __restrict__ out) {
  __shared__ float As[64][36];
  __shared__ float Bs[64][132];
  const int t = threadIdx.x;
  const int row0 = blockIdx.x * 32;
  const int tr = t & 7, tc = t >> 3;
  float sum[4][4];
#pragma unroll
  for (int i = 0; i < 4; i++)
#pragma unroll
    for (int j = 0; j < 4; j++) sum[i][j] = 0.f;

  for (int head = 0; head < NHD; head++) {
    const float* Ah = A + (size_t)head * Nn * Cc;
    const float* Bh = Bw + (size_t)head * Cc * Cc;
    float acc[4][4];
#pragma unroll
    for (int i = 0; i < 4; i++)
#pragma unroll
      for (int j = 0; j < 4; j++) acc[i][j] = 0.f;

    for (int kt = 0; kt < Cc; kt += 64) {
      __syncthreads();
      for (int i = t; i < 512; i += 256) {
        int rr = i >> 4, k4 = i & 15;
        float4 v = *(const float4*)(Ah + (size_t)(row0 + rr) * Cc + kt + k4 * 4);
        As[k4 * 4 + 0][rr] = v.x; As[k4 * 4 + 1][rr] = v.y;
        As[k4 * 4 + 2][rr] = v.z; As[k4 * 4 + 3][rr] = v.w;
      }
      for (int i = t; i < 2048; i += 256) {
        int cc2 = i >> 4, k4 = i & 15;
        float4 v = *(const float4*)(Bh + (size_t)cc2 * Cc + kt + k4 * 4);
        Bs[k4 * 4 + 0][cc2] = v.x; Bs[k4 * 4 + 1][cc2] = v.y;
        Bs[k4 * 4 + 2][cc2] = v.z; Bs[k4 * 4 + 3][cc2] = v.w;
      }
      __syncthreads();
#pragma unroll
      for (int k = 0; k < 64; k++) {
        float4 a4 = *(const float4*)&As[k][tr * 4];
        float4 b4 = *(const float4*)&Bs[k][tc * 4];
        float av[4] = {a4.x, a4.y, a4.z, a4.w};
        float bv[4] = {b4.x, b4.y, b4.z, b4.w};
#pragma unroll
        for (int i = 0; i < 4; i++)
#pragma unroll
          for (int j = 0; j < 4; j++) acc[i][j] = fmaf(av[i], bv[j], acc[i][j]);
      }
    }
#pragma unroll
    for (int i = 0; i < 4; i++)
#pragma unroll
      for (int j = 0; j < 4; j++) {
        float v = acc[i][j];
        v = (v > 0.f) ? v : (expf(v) - 1.f);
        sum[i][j] = fmaf(v, 0.5f, sum[i][j]);
      }
  }
#pragma unroll
  for (int i = 0; i < 4; i++) {
    float* op = out + (size_t)(row0 + tr * 4 + i) * Cc + tc * 4;
    *(float4*)op = make_float4(sum[i][0], sum[i][1], sum[i][2], sum[i][3]);
  }
}

extern "C" void kernel_launch(void* const* d_in, const int* in_sizes, int n_in,
                              void* d_out, int out_size, void* d_ws, size_t ws_size,
                              hipStream_t stream) {
  const float* x   = (const float*)d_in[0];
  const float* adj = (const float*)d_in[1];
  const float* ff0 = (const float*)d_in[2];
  const float* ff1 = (const float*)d_in[3];
  const float* aw  = (const float*)d_in[4];
  const float* g1  = (const float*)d_in[5];
  const float* b1  = (const float*)d_in[6];
  const float* g2  = (const float*)d_in[7];
  const float* b2  = (const float*)d_in[8];
  float* out = (float*)d_out;

  float* ws   = (float*)d_ws;
  float* h    = ws;                                  // 2*Nn*Cc
  float* ssrc = h + (size_t)2 * Nn * Cc;             // 2*Nn
  float* sdst = ssrc + 2 * Nn;                       // 2*Nn
  float* attn = sdst + 2 * Nn;                       // 2*Nn*Cc
  int* degp   = (int*)(attn + (size_t)2 * Nn * Cc);  // Nn
  int* nbrg   = degp + Nn;                           // Nn*GMAXDEG
  // total ws use: ~19 MB

  hipLaunchKernelGGL(k_scan, dim3(Nn), dim3(256), 0, stream, adj, degp, nbrg);
  hipLaunchKernelGGL(k_ff0_fused, dim3(Nn / 32, NHD), dim3(256), 0, stream,
                     x, g1, b1, ff0, aw, h, ssrc, sdst);
  hipLaunchKernelGGL(k_attn, dim3(Nn), dim3(256), 0, stream,
                     degp, nbrg, x, h, ssrc, sdst, g2, b2, attn);
  hipLaunchKernelGGL(k_ff1_comb, dim3(Nn / 32), dim3(256), 0, stream, attn, ff1, out);
}

// Round 9
// 301.195 us; speedup vs baseline: 1.1125x; 1.0099x over previous
//
#include <hip/hip_runtime.h>
#include <math.h>

#define Nn 6144
#define Cc 128
#define NHD 2
#define GMAXDEG 256  // deg ~ Binomial(6144,0.01): mean 61, sd 7.8; 256 = +25 sigma
#define FF0_BLOCKS 384  // (Nn/32) * NHD

// ---------------- warp/block reduction helpers ----------------
__device__ __forceinline__ float wave_red_sum(float v) {
#pragma unroll
  for (int o = 32; o; o >>= 1) v += __shfl_xor(v, o);
  return v;
}

template <bool IS_MAX>
__device__ __forceinline__ void block_red2(float& a, float& b, float* red) {
#pragma unroll
  for (int o = 32; o; o >>= 1) {
    float ta = __shfl_xor(a, o), tb = __shfl_xor(b, o);
    if (IS_MAX) { a = fmaxf(a, ta); b = fmaxf(b, tb); }
    else        { a += ta;          b += tb;          }
  }
  int wid = threadIdx.x >> 6;
  __syncthreads();
  if ((threadIdx.x & 63) == 0) { red[wid] = a; red[4 + wid] = b; }
  __syncthreads();
  if (IS_MAX) {
    a = fmaxf(fmaxf(red[0], red[1]), fmaxf(red[2], red[3]));
    b = fmaxf(fmaxf(red[4], red[5]), fmaxf(red[6], red[7]));
  } else {
    a = red[0] + red[1] + red[2] + red[3];
    b = red[4] + red[5] + red[6] + red[7];
  }
}

// ---------------- k_front: block-specialized {FF0-fused | adjacency scan} ---
// Blocks [0, 384): LN + FF0 GEMM + attn_s (identical math to round-8
// k_ff0_fused). Blocks [384, 6528): adjacency scan -> CSR (identical to
// round-8 k_scan). The two paths are data-independent; specialization
// overlaps the HBM-bound scan under the compute-bound GEMM in ONE launch.
__global__ __launch_bounds__(256) void k_front(
    const float* __restrict__ x, const float* __restrict__ g1,
    const float* __restrict__ b1, const float* __restrict__ Bw,
    const float* __restrict__ aw, const float* __restrict__ adj,
    float* __restrict__ h, float* __restrict__ ssrc,
    float* __restrict__ sdst, int* __restrict__ degp,
    int* __restrict__ nbrg) {
  __shared__ __align__(16) float smem[128 * 36 + 64 * 132];  // 52.2 KB
  const int t = threadIdx.x;
  const int bid = blockIdx.x;

  if (bid >= FF0_BLOCKS) {
    // ---------------- scan path ----------------
    int* nbr = (int*)smem;
    __shared__ int cnt;
    const int r = bid - FF0_BLOCKS;
    if (t == 0) cnt = 0;
    __syncthreads();
    const float4* arow = (const float4*)(adj + (size_t)r * Nn);
    for (int i = t; i < Nn / 4; i += 256) {
      float4 v = arow[i];
      int j = i * 4;
      if (v.x > 0.f || j + 0 == r) { int p = atomicAdd(&cnt, 1); if (p < GMAXDEG) nbr[p] = j + 0; }
      if (v.y > 0.f || j + 1 == r) { int p = atomicAdd(&cnt, 1); if (p < GMAXDEG) nbr[p] = j + 1; }
      if (v.z > 0.f || j + 2 == r) { int p = atomicAdd(&cnt, 1); if (p < GMAXDEG) nbr[p] = j + 2; }
      if (v.w > 0.f || j + 3 == r) { int p = atomicAdd(&cnt, 1); if (p < GMAXDEG) nbr[p] = j + 3; }
    }
    __syncthreads();
    const int d = min(cnt, GMAXDEG);
    if (t == 0) degp[r] = d;
    for (int k = t; k < d; k += 256) nbrg[(size_t)r * GMAXDEG + k] = nbr[k];
    return;
  }

  // ---------------- ff0 path ----------------
  float (*Axn)[36] = (float(*)[36])smem;                  // [128][36]
  float (*Bs)[132] = (float(*)[132])(smem + 128 * 36);    // [64][132]
  const int head = bid & 1;
  const int row0 = (bid >> 1) * 32;
  const float* Bh = Bw + (size_t)head * Cc * Cc;

  {
    const int row = t >> 3, seg = t & 7;
    const int cb = seg * 16;
    const float* xr = x + (size_t)(row0 + row) * Cc + cb;
    float v[16], gg[16], bb[16];
#pragma unroll
    for (int i = 0; i < 16; i += 4) {
      float4 t4 = *(const float4*)(xr + i);
      v[i] = t4.x; v[i + 1] = t4.y; v[i + 2] = t4.z; v[i + 3] = t4.w;
      float4 g4 = *(const float4*)(g1 + cb + i);
      gg[i] = g4.x; gg[i + 1] = g4.y; gg[i + 2] = g4.z; gg[i + 3] = g4.w;
      float4 b4 = *(const float4*)(b1 + cb + i);
      bb[i] = b4.x; bb[i + 1] = b4.y; bb[i + 2] = b4.z; bb[i + 3] = b4.w;
    }
    float s = 0.f;
#pragma unroll
    for (int i = 0; i < 16; i++) s += v[i];
    s += __shfl_xor(s, 1); s += __shfl_xor(s, 2); s += __shfl_xor(s, 4);
    float mean = s * (1.0f / 128.0f);
    float q = 0.f;
#pragma unroll
    for (int i = 0; i < 16; i++) { float d_ = v[i] - mean; q += d_ * d_; }
    q += __shfl_xor(q, 1); q += __shfl_xor(q, 2); q += __shfl_xor(q, 4);
    float rstd = rsqrtf(q * (1.0f / 128.0f) + 1e-5f);
#pragma unroll
    for (int i = 0; i < 16; i++)
      Axn[cb + i][row] = (v[i] - mean) * rstd * gg[i] + bb[i];
  }
  __syncthreads();

  const int tr = t & 7, tc = t >> 3;
  float acc[4][4];
#pragma unroll
  for (int i = 0; i < 4; i++)
#pragma unroll
    for (int j = 0; j < 4; j++) acc[i][j] = 0.f;

  for (int kt = 0; kt < Cc; kt += 64) {
    for (int i = t; i < 2048; i += 256) {
      int cc2 = i >> 4, k4 = i & 15;
      float4 v = *(const float4*)(Bh + (size_t)cc2 * Cc + kt + k4 * 4);
      Bs[k4 * 4 + 0][cc2] = v.x; Bs[k4 * 4 + 1][cc2] = v.y;
      Bs[k4 * 4 + 2][cc2] = v.z; Bs[k4 * 4 + 3][cc2] = v.w;
    }
    __syncthreads();
#pragma unroll
    for (int k = 0; k < 64; k++) {
      float4 a4 = *(const float4*)&Axn[kt + k][tr * 4];
      float4 b4 = *(const float4*)&Bs[k][tc * 4];
      float av[4] = {a4.x, a4.y, a4.z, a4.w};
      float bv[4] = {b4.x, b4.y, b4.z, b4.w};
#pragma unroll
      for (int i = 0; i < 4; i++)
#pragma unroll
        for (int j = 0; j < 4; j++) acc[i][j] = fmaf(av[i], bv[j], acc[i][j]);
    }
    __syncthreads();
  }

  float psrc[4], pdst[4];
  {
    float4 w1 = *(const float4*)(aw + head * 2 * Cc + tc * 4);
    float4 w2 = *(const float4*)(aw + head * 2 * Cc + Cc + tc * 4);
#pragma unroll
    for (int i = 0; i < 4; i++) {
      float* op = h + ((size_t)head * Nn + row0 + tr * 4 + i) * Cc + tc * 4;
      *(float4*)op = make_float4(acc[i][0], acc[i][1], acc[i][2], acc[i][3]);
      psrc[i] = acc[i][0] * w1.x + acc[i][1] * w1.y + acc[i][2] * w1.z + acc[i][3] * w1.w;
      pdst[i] = acc[i][0] * w2.x + acc[i][1] * w2.y + acc[i][2] * w2.z + acc[i][3] * w2.w;
    }
  }
  float* epart = &Bs[0][0];  // [32 tc][32 row][2]
#pragma unroll
  for (int i = 0; i < 4; i++) {
    epart[((tc * 32) + (tr * 4 + i)) * 2 + 0] = psrc[i];
    epart[((tc * 32) + (tr * 4 + i)) * 2 + 1] = pdst[i];
  }
  __syncthreads();
  if (t < 64) {
    int row = t >> 1, s = t & 1;
    float v = 0.f;
#pragma unroll
    for (int g = 0; g < 32; g++) v += epart[(g * 32 + row) * 2 + s];
    (s ? sdst : ssrc)[head * Nn + row0 + row] = v;
  }
}

// ---------------- kernel 3: CSR attention + residual + LN2 ------------------
// UNCHANGED from round-8 verified version (control).
__global__ __launch_bounds__(256) void k_attn(
    const int* __restrict__ degp, const int* __restrict__ nbrg,
    const float* __restrict__ x, const float* __restrict__ h,
    const float* __restrict__ ssrc, const float* __restrict__ sdst,
    const float* __restrict__ g2, const float* __restrict__ b2,
    float* __restrict__ att_out) {
  __shared__ __align__(16) int nbr[GMAXDEG];
  __shared__ __align__(16) float wts[NHD][GMAXDEG];
  __shared__ __align__(16) float4 part[256];
  __shared__ float red[8];
  const int t = threadIdx.x;
  const int r = blockIdx.x;
  const int deg = degp[r];
  for (int k = t; k < deg; k += 256) nbr[k] = nbrg[(size_t)r * GMAXDEG + k];
  __syncthreads();
  const float s0 = ssrc[r], s1 = ssrc[Nn + r];
  float m0 = -3.0e38f, m1 = -3.0e38f;
  for (int k = t; k < deg; k += 256) {
    int j = nbr[k];
    float e0 = s0 + sdst[j];
    float e1 = s1 + sdst[Nn + j];
    e0 = (e0 > 0.f) ? e0 : 0.01f * e0;
    e1 = (e1 > 0.f) ? e1 : 0.01f * e1;
    wts[0][k] = e0; wts[1][k] = e1;
    m0 = fmaxf(m0, e0); m1 = fmaxf(m1, e1);
  }
  block_red2<true>(m0, m1, red);
  float l0 = 0.f, l1 = 0.f;
  for (int k = t; k < deg; k += 256) {
    float w0 = __expf(wts[0][k] - m0); wts[0][k] = w0; l0 += w0;
    float w1 = __expf(wts[1][k] - m1); wts[1][k] = w1; l1 += w1;
  }
  block_red2<false>(l0, l1, red);
  {
    const int hd = t >> 7, g = (t >> 5) & 3, c4 = t & 31;
    const float* hp = h + (size_t)hd * Nn * Cc + c4 * 4;
    float4 a4 = make_float4(0.f, 0.f, 0.f, 0.f);
#pragma unroll 2
    for (int k = g; k < deg; k += 4) {
      float w = wts[hd][k];
      const float4 hv = *(const float4*)(hp + (size_t)nbr[k] * Cc);
      a4.x = fmaf(w, hv.x, a4.x);
      a4.y = fmaf(w, hv.y, a4.y);
      a4.z = fmaf(w, hv.z, a4.z);
      a4.w = fmaf(w, hv.w, a4.w);
    }
    __syncthreads();
    part[t] = a4;
    __syncthreads();
    float* attbuf = (float*)nbr;
    if (t < 64) {
      const int hd2 = t >> 5, cb = t & 31;
      float4 p0 = part[hd2 * 128 + 0  + cb];
      float4 p1 = part[hd2 * 128 + 32 + cb];
      float4 p2 = part[hd2 * 128 + 64 + cb];
      float4 p3 = part[hd2 * 128 + 96 + cb];
      float sx_ = p0.x + p1.x + p2.x + p3.x;
      float sy_ = p0.y + p1.y + p2.y + p3.y;
      float sz_ = p0.z + p1.z + p2.z + p3.z;
      float sw_ = p0.w + p1.w + p2.w + p3.w;
      const float inv2 = 1.0f / (hd2 ? l1 : l0);
      const float4 xv = *(const float4*)(x + (size_t)r * Cc + cb * 4);
      float4 att4;
      att4.x = fmaf(sx_, inv2, xv.x);
      att4.y = fmaf(sy_, inv2, xv.y);
      att4.z = fmaf(sz_, inv2, xv.z);
      att4.w = fmaf(sw_, inv2, xv.w);
      ((float4*)attbuf)[hd2 * 32 + cb] = att4;
    }
    __syncthreads();
  }
  {
    const int hd = t >> 7, c = t & 127;
    float att = ((float*)nbr)[hd * 128 + c];
    float s = wave_red_sum(att);
    int wid = t >> 6;
    __syncthreads();
    if ((t & 63) == 0) red[wid] = s;
    __syncthreads();
    float mean = (red[hd * 2] + red[hd * 2 + 1]) * (1.0f / Cc);
    float d = att - mean;
    float q = wave_red_sum(d * d);
    __syncthreads();
    if ((t & 63) == 0) red[wid] = q;
    __syncthreads();
    float var = (red[hd * 2] + red[hd * 2 + 1]) * (1.0f / Cc);
    float rstd = rsqrtf(var + 1e-5f);
    att_out[((size_t)hd * Nn + r) * Cc + c] = d * rstd * g2[c] + b2[c];
  }
}

// ---------------- fused FF1 GEMM + head-combine, 32-row tiles ---------------
// UNCHANGED from round-8 verified version (control).
__global__ __launch_bounds__(256) void k_ff1_comb(const float* __restrict__ A,
                                                  const float* __restrict__ Bw,
                                                  float* __restrict__ out) {
  __shared__ float As[64][36];
  __shared__ float Bs[64][132];
  const int t = threadIdx.x;
  const int row0 = blockIdx.x * 32;
  const int tr = t & 7, tc = t >> 3;
  float sum[4][4];
#pragma unroll
  for (int i = 0; i < 4; i++)
#pragma unroll
    for (int j = 0; j < 4; j++) sum[i][j] = 0.f;

  for (int head = 0; head < NHD; head++) {
    const float* Ah = A + (size_t)head * Nn * Cc;
    const float* Bh = Bw + (size_t)head * Cc * Cc;
    float acc[4][4];
#pragma unroll
    for (int i = 0; i < 4; i++)
#pragma unroll
      for (int j = 0; j < 4; j++) acc[i][j] = 0.f;

    for (int kt = 0; kt < Cc; kt += 64) {
      __syncthreads();
      for (int i = t; i < 512; i += 256) {
        int rr = i >> 4, k4 = i & 15;
        float4 v = *(const float4*)(Ah + (size_t)(row0 + rr) * Cc + kt + k4 * 4);
        As[k4 * 4 + 0][rr] = v.x; As[k4 * 4 + 1][rr] = v.y;
        As[k4 * 4 + 2][rr] = v.z; As[k4 * 4 + 3][rr] = v.w;
      }
      for (int i = t; i < 2048; i += 256) {
        int cc2 = i >> 4, k4 = i & 15;
        float4 v = *(const float4*)(Bh + (size_t)cc2 * Cc + kt + k4 * 4);
        Bs[k4 * 4 + 0][cc2] = v.x; Bs[k4 * 4 + 1][cc2] = v.y;
        Bs[k4 * 4 + 2][cc2] = v.z; Bs[k4 * 4 + 3][cc2] = v.w;
      }
      __syncthreads();
#pragma unroll
      for (int k = 0; k < 64; k++) {
        float4 a4 = *(const float4*)&As[k][tr * 4];
        float4 b4 = *(const float4*)&Bs[k][tc * 4];
        float av[4] = {a4.x, a4.y, a4.z, a4.w};
        float bv[4] = {b4.x, b4.y, b4.z, b4.w};
#pragma unroll
        for (int i = 0; i < 4; i++)
#pragma unroll
          for (int j = 0; j < 4; j++) acc[i][j] = fmaf(av[i], bv[j], acc[i][j]);
      }
    }
#pragma unroll
    for (int i = 0; i < 4; i++)
#pragma unroll
      for (int j = 0; j < 4; j++) {
        float v = acc[i][j];
        v = (v > 0.f) ? v : (expf(v) - 1.f);
        sum[i][j] = fmaf(v, 0.5f, sum[i][j]);
      }
  }
#pragma unroll
  for (int i = 0; i < 4; i++) {
    float* op = out + (size_t)(row0 + tr * 4 + i) * Cc + tc * 4;
    *(float4*)op = make_float4(sum[i][0], sum[i][1], sum[i][2], sum[i][3]);
  }
}

extern "C" void kernel_launch(void* const* d_in, const int* in_sizes, int n_in,
                              void* d_out, int out_size, void* d_ws, size_t ws_size,
                              hipStream_t stream) {
  const float* x   = (const float*)d_in[0];
  const float* adj = (const float*)d_in[1];
  const float* ff0 = (const float*)d_in[2];
  const float* ff1 = (const float*)d_in[3];
  const float* aw  = (const float*)d_in[4];
  const float* g1  = (const float*)d_in[5];
  const float* b1  = (const float*)d_in[6];
  const float* g2  = (const float*)d_in[7];
  const float* b2  = (const float*)d_in[8];
  float* out = (float*)d_out;

  float* ws   = (float*)d_ws;
  float* h    = ws;                                  // 2*Nn*Cc
  float* ssrc = h + (size_t)2 * Nn * Cc;             // 2*Nn
  float* sdst = ssrc + 2 * Nn;                       // 2*Nn
  float* attn = sdst + 2 * Nn;                       // 2*Nn*Cc
  int* degp   = (int*)(attn + (size_t)2 * Nn * Cc);  // Nn
  int* nbrg   = degp + Nn;                           // Nn*GMAXDEG
  // total ws use: ~19 MB

  hipLaunchKernelGGL(k_front, dim3(FF0_BLOCKS + Nn), dim3(256), 0, stream,
                     x, g1, b1, ff0, aw, adj, h, ssrc, sdst, degp, nbrg);
  hipLaunchKernelGGL(k_attn, dim3(Nn), dim3(256), 0, stream,
                     degp, nbrg, x, h, ssrc, sdst, g2, b2, attn);
  hipLaunchKernelGGL(k_ff1_comb, dim3(Nn / 32), dim3(256), 0, stream, attn, ff1, out);
}